// Round 3
// baseline (359.398 us; speedup 1.0000x reference)
//
#include <hip/hip_runtime.h>

#define K 64
#define S_CHUNK 128
#define W_BURN 160
#define BATCH 16

typedef __attribute__((ext_vector_type(4))) _Float16 half4;
typedef __attribute__((ext_vector_type(4))) float f32x4;

__device__ __forceinline__ float waveReduceSum(float v) {
#pragma unroll
    for (int off = 32; off > 0; off >>= 1) v += __shfl_xor(v, off, 64);
    return v;
}

// ws layout (float offsets)
#define WS_P     0      // P row-major [64][64] f32
#define WS_PI    4096
#define WS_UTT0  4160
#define WS_ISG   4224   // 1/sigma
#define WS_NNU   4288   // -mu/sigma
#define WS_L2N   4352   // log2(1/(sigma*sqrt(2pi)))

// One wave: softmax(P), stationary pi (power iteration), emission params, row-0 outputs.
__global__ __launch_bounds__(64) void hmm_setup(
    const float* __restrict__ y, const float* __restrict__ logits,
    const float* __restrict__ mu, const float* __restrict__ log_sigma,
    float* __restrict__ out, float* __restrict__ ws, int T)
{
    __shared__ float P[K][K];
    __shared__ float pib[K];
    const int k = threadIdx.x;

    float row[K]; float m = -3.4e38f;
#pragma unroll
    for (int i = 0; i < K; ++i) { row[i] = logits[k*K + i]; m = fmaxf(m, row[i]); }
    float s = 0.f;
#pragma unroll
    for (int i = 0; i < K; ++i) { row[i] = __expf(row[i] - m); s += row[i]; }
    float inv = 1.0f / s;
#pragma unroll
    for (int i = 0; i < K; ++i) { float p = row[i]*inv; P[k][i] = p; ws[WS_P + k*K + i] = p; }
    __syncthreads();

    pib[k] = 1.0f/64.0f;
    __syncthreads();
    for (int it = 0; it < 64; ++it) {
        float acc = 0.f;
#pragma unroll
        for (int j = 0; j < K; ++j) acc += pib[j]*P[j][k];   // (pi^T P)_k
        float tot = waveReduceSum(acc);
        acc /= tot;
        __syncthreads();
        pib[k] = acc;
        __syncthreads();
    }
    float pi_k = pib[k];

    float mu_k = mu[k];
    float isg = __expf(-log_sigma[k]);            // 1/sigma
    float inorm = isg * 0.39894228040143267f;     // 1/(sigma*sqrt(2pi))

    ws[WS_PI  + k] = pi_k;
    ws[WS_ISG + k] = isg;
    ws[WS_NNU + k] = -mu_k * isg;
    ws[WS_L2N + k] = __log2f(inorm);

    float y0 = y[0];
    float z = (y0 - mu_k) * isg;
    float g0 = __expf(-0.5f*z*z) * inorm;
    float num = pi_k * g0;
    float ft0 = waveReduceSum(num);
    float utt0 = num / ft0;
    ws[WS_UTT0 + k] = utt0;

    out[k] = pi_k;                       // ut[0]
    out[(size_t)T*K + k] = utt0;         // unorm[0]
    if (k == 0) out[(size_t)2*T*K] = ft0;// ft[0]
}

// One wave = 16 chunks, lockstep. beta kept NORMALIZED in f16 B-fragments.
// v^T = P^T * beta^T via 16x v_mfma_f32_16x16x16f16; C-frag layout == B-frag
// layout, so next step's operand is an in-register cvt_pkrtz of this step's
// normalized result. ut[t] = v, ft[t] = sum(v*g), unorm[t] = v*g/ft.
__global__ __launch_bounds__(64) void hmm_scan(
    const float* __restrict__ y, const float* __restrict__ ws,
    float* __restrict__ out, int T)
{
    const int lane = threadIdx.x;
    const int c = lane & 15;          // chunk slot / matrix column
    const int q = lane >> 4;          // lane group
    const int NCH = (T + S_CHUNK - 1) / S_CHUNK;
    const int cg = blockIdx.x * BATCH + c;
    const int t0 = cg * S_CHUNK;

    // A fragments: A(nb,kb)[i][kk] = P[16kb+kk][16nb+i]  (i = c = lane&15, kk = 4q+j)
    half4 a[4][4];
#pragma unroll
    for (int nb = 0; nb < 4; ++nb)
#pragma unroll
        for (int kb = 0; kb < 4; ++kb)
#pragma unroll
            for (int j = 0; j < 4; ++j)
                a[nb][kb][j] = (_Float16)ws[WS_P + (16*kb + 4*q + j)*K + 16*nb + c];

    // emission constants for this lane's 16 output states: s = 16nb + 4q + r
    f32x4 isg_[4], nnu_[4], l2n_[4];
#pragma unroll
    for (int nb = 0; nb < 4; ++nb)
#pragma unroll
        for (int r = 0; r < 4; ++r) {
            int s = 16*nb + 4*q + r;
            isg_[nb][r] = ws[WS_ISG + s];
            nnu_[nb][r] = ws[WS_NNU + s];
            l2n_[nb][r] = ws[WS_L2N + s];
        }

    // B fragments: beta of chunk c at states 16kb+4q+j
    half4 bfr[4], u0h[4];
#pragma unroll
    for (int kb = 0; kb < 4; ++kb)
#pragma unroll
        for (int j = 0; j < 4; ++j) {
            int s = 16*kb + 4*q + j;
            bfr[kb][j] = (_Float16)ws[WS_PI + s];
            u0h[kb][j] = (_Float16)ws[WS_UTT0 + s];
        }

    const int tlo = (cg == 0) ? 1 : ((cg < NCH) ? 0 : 0x7fffffff);
    int tcur = t0 - W_BURN;

    float* po = out + (size_t)t0 * K + 4*q;
    float* pu = po + (size_t)T * K;
    float* pf = out + (size_t)2 * T * K + t0;

    // y comes in aligned groups of 4 (t0 and W_BURN are multiples of 4),
    // prefetched one group (4 steps) ahead. Clamped addresses feed finite
    // garbage to chunk-0 burn-in (state overridden at t=0) and tail lanes
    // (stores predicated off).
    int ib = min(max(tcur, 0), T - 4);
    f32x4 yv = *(const f32x4*)(y + ib);

#define STEP(OUTP, YCUR) do {                                                  \
    f32x4 acc[4] = {{0.f,0.f,0.f,0.f},{0.f,0.f,0.f,0.f},                       \
                    {0.f,0.f,0.f,0.f},{0.f,0.f,0.f,0.f}};                      \
    _Pragma("unroll")                                                          \
    for (int kb = 0; kb < 4; ++kb) {                                           \
        _Pragma("unroll")                                                      \
        for (int nb = 0; nb < 4; ++nb)                                         \
            acc[nb] = __builtin_amdgcn_mfma_f32_16x16x16f16(                   \
                a[nb][kb], bfr[kb], acc[nb], 0, 0, 0);                         \
    }                                                                          \
    const bool pred = (tcur >= tlo) & (tcur < T);                              \
    if (OUTP && pred) {                                                        \
        _Pragma("unroll")                                                      \
        for (int nb = 0; nb < 4; ++nb)                                         \
            __builtin_nontemporal_store(acc[nb], (f32x4*)(po + 16*nb));        \
    }                                                                          \
    f32x4 nrm[4]; float st = 0.f;                                              \
    _Pragma("unroll")                                                          \
    for (int nb = 0; nb < 4; ++nb) {                                           \
        _Pragma("unroll")                                                      \
        for (int r = 0; r < 4; ++r) {                                          \
            float z  = fmaf(YCUR, isg_[nb][r], nnu_[nb][r]);                   \
            float ag = fmaf(z*z, -0.72134752f, l2n_[nb][r]);                   \
            float g  = __builtin_amdgcn_exp2f(ag);                             \
            nrm[nb][r] = acc[nb][r] * g;                                       \
            st += nrm[nb][r];                                                  \
        }                                                                      \
    }                                                                          \
    st += __shfl_xor(st, 16, 64);                                              \
    st += __shfl_xor(st, 32, 64);                                              \
    const float rs = __builtin_amdgcn_rcpf(st);                                \
    _Pragma("unroll")                                                          \
    for (int nb = 0; nb < 4; ++nb) nrm[nb] *= rs;                              \
    if (OUTP && pred) {                                                        \
        _Pragma("unroll")                                                      \
        for (int nb = 0; nb < 4; ++nb)                                         \
            __builtin_nontemporal_store(nrm[nb], (f32x4*)(pu + 16*nb));        \
        if (lane < 16) __builtin_nontemporal_store(st, pf);                    \
    }                                                                          \
    _Pragma("unroll")                                                          \
    for (int kb = 0; kb < 4; ++kb) {                                           \
        auto lo = __builtin_amdgcn_cvt_pkrtz(nrm[kb][0], nrm[kb][1]);          \
        auto hi = __builtin_amdgcn_cvt_pkrtz(nrm[kb][2], nrm[kb][3]);          \
        bfr[kb][0] = (_Float16)lo[0]; bfr[kb][1] = (_Float16)lo[1];            \
        bfr[kb][2] = (_Float16)hi[0]; bfr[kb][3] = (_Float16)hi[1];            \
    }                                                                          \
    if (OUTP) { po += K; pu += K; pf += 1; }                                   \
    ++tcur;                                                                    \
} while (0)

    // burn-in: 160 steps, no stores
#pragma unroll 1
    for (int gi = 0; gi < W_BURN/4; ++gi) {
        int ibn = min(max(tcur + 4, 0), T - 4);
        f32x4 yn = *(const f32x4*)(y + ibn);
        STEP(0, yv[0]); STEP(0, yv[1]); STEP(0, yv[2]); STEP(0, yv[3]);
        yv = yn;
    }
    // output group 0 (peeled: chunk-0 state override after t=0 step)
    {
        int ibn = min(max(tcur + 4, 0), T - 4);
        f32x4 yn = *(const f32x4*)(y + ibn);
        STEP(1, yv[0]);
        if (cg == 0) { bfr[0]=u0h[0]; bfr[1]=u0h[1]; bfr[2]=u0h[2]; bfr[3]=u0h[3]; }
        STEP(1, yv[1]); STEP(1, yv[2]); STEP(1, yv[3]);
        yv = yn;
    }
#pragma unroll 1
    for (int gi = 1; gi < S_CHUNK/4; ++gi) {
        int ibn = min(max(tcur + 4, 0), T - 4);
        f32x4 yn = *(const f32x4*)(y + ibn);
        STEP(1, yv[0]); STEP(1, yv[1]); STEP(1, yv[2]); STEP(1, yv[3]);
        yv = yn;
    }
#undef STEP
}

extern "C" void kernel_launch(void* const* d_in, const int* in_sizes, int n_in,
                              void* d_out, int out_size, void* d_ws, size_t ws_size,
                              hipStream_t stream) {
    const float* y      = (const float*)d_in[0];
    const float* logits = (const float*)d_in[1];
    const float* mu     = (const float*)d_in[2];
    const float* lsig   = (const float*)d_in[3];
    float* out = (float*)d_out;
    float* ws  = (float*)d_ws;
    const int T = in_sizes[0];

    hmm_setup<<<1, 64, 0, stream>>>(y, logits, mu, lsig, out, ws, T);

    const int nch  = (T + S_CHUNK - 1) / S_CHUNK;
    const int nblk = (nch + BATCH - 1) / BATCH;
    hmm_scan<<<nblk, 64, 0, stream>>>(y, ws, out, T);
}

// Round 4
// 229.593 us; speedup vs baseline: 1.5654x; 1.5654x over previous
//
#include <hip/hip_runtime.h>

#define K 64
#define S_CHUNK 128
#define W_BURN 160
#define BATCH 16

typedef __attribute__((ext_vector_type(4))) _Float16 half4;
typedef __attribute__((ext_vector_type(4))) float f32x4;

__device__ __forceinline__ float waveReduceSum(float v) {
#pragma unroll
    for (int off = 32; off > 0; off >>= 1) v += __shfl_xor(v, off, 64);
    return v;
}

// ws layout (float offsets)
#define WS_P     0      // P row-major [64][64] f32
#define WS_PI    4096
#define WS_UTT0  4160
#define WS_ISG   4224   // 1/sigma
#define WS_NNU   4288   // -mu/sigma
#define WS_L2N   4352   // log2(1/(sigma*sqrt(2pi)))

// One wave: softmax(P), stationary pi (power iteration), emission params, row-0 outputs.
__global__ __launch_bounds__(64) void hmm_setup(
    const float* __restrict__ y, const float* __restrict__ logits,
    const float* __restrict__ mu, const float* __restrict__ log_sigma,
    float* __restrict__ out, float* __restrict__ ws, int T)
{
    __shared__ float P[K][K];
    __shared__ float pib[K];
    const int k = threadIdx.x;

    float row[K]; float m = -3.4e38f;
#pragma unroll
    for (int i = 0; i < K; ++i) { row[i] = logits[k*K + i]; m = fmaxf(m, row[i]); }
    float s = 0.f;
#pragma unroll
    for (int i = 0; i < K; ++i) { row[i] = __expf(row[i] - m); s += row[i]; }
    float inv = 1.0f / s;
#pragma unroll
    for (int i = 0; i < K; ++i) { float p = row[i]*inv; P[k][i] = p; ws[WS_P + k*K + i] = p; }
    __syncthreads();

    pib[k] = 1.0f/64.0f;
    __syncthreads();
    for (int it = 0; it < 64; ++it) {
        float acc = 0.f;
#pragma unroll
        for (int j = 0; j < K; ++j) acc += pib[j]*P[j][k];   // (pi^T P)_k
        float tot = waveReduceSum(acc);
        acc /= tot;
        __syncthreads();
        pib[k] = acc;
        __syncthreads();
    }
    float pi_k = pib[k];

    float mu_k = mu[k];
    float isg = __expf(-log_sigma[k]);            // 1/sigma
    float inorm = isg * 0.39894228040143267f;     // 1/(sigma*sqrt(2pi))

    ws[WS_PI  + k] = pi_k;
    ws[WS_ISG + k] = isg;
    ws[WS_NNU + k] = -mu_k * isg;
    ws[WS_L2N + k] = __log2f(inorm);

    float y0 = y[0];
    float z = (y0 - mu_k) * isg;
    float g0 = __expf(-0.5f*z*z) * inorm;
    float num = pi_k * g0;
    float ft0 = waveReduceSum(num);
    float utt0 = num / ft0;
    ws[WS_UTT0 + k] = utt0;

    out[k] = pi_k;                       // ut[0]
    out[(size_t)T*K + k] = utt0;         // unorm[0]
    if (k == 0) out[(size_t)2*T*K] = ft0;// ft[0]
}

// One wave = 16 chunks, lockstep. beta kept NORMALIZED in f16 B-fragments.
// v^T = P^T * beta^T via 16x v_mfma_f32_16x16x16f16; C-frag layout == B-frag
// layout, so next step's operand is an in-register cvt_pkrtz of this step's
// normalized result. ut[t] = v, ft[t] = sum(v*g), unorm[t] = v*g/ft.
// Plain cached stores: L2 coalesces the per-chunk 64B fragments into full
// lines (R3's nontemporal stores caused 1.43x write amplification + partial
// bursts => 2.3 TB/s write ceiling).
__global__ __launch_bounds__(64) void hmm_scan(
    const float* __restrict__ y, const float* __restrict__ ws,
    float* __restrict__ out, int T)
{
    const int lane = threadIdx.x;
    const int c = lane & 15;          // chunk slot / matrix column
    const int q = lane >> 4;          // lane group
    const int NCH = (T + S_CHUNK - 1) / S_CHUNK;
    const int cg = blockIdx.x * BATCH + c;
    const int t0 = cg * S_CHUNK;

    // A fragments: A(nb,kb)[i][kk] = P[16kb+kk][16nb+i]  (i = c = lane&15, kk = 4q+j)
    half4 a[4][4];
#pragma unroll
    for (int nb = 0; nb < 4; ++nb)
#pragma unroll
        for (int kb = 0; kb < 4; ++kb)
#pragma unroll
            for (int j = 0; j < 4; ++j)
                a[nb][kb][j] = (_Float16)ws[WS_P + (16*kb + 4*q + j)*K + 16*nb + c];

    // emission constants for this lane's 16 output states: s = 16nb + 4q + r
    f32x4 isg_[4], nnu_[4], l2n_[4];
#pragma unroll
    for (int nb = 0; nb < 4; ++nb)
#pragma unroll
        for (int r = 0; r < 4; ++r) {
            int s = 16*nb + 4*q + r;
            isg_[nb][r] = ws[WS_ISG + s];
            nnu_[nb][r] = ws[WS_NNU + s];
            l2n_[nb][r] = ws[WS_L2N + s];
        }

    // B fragments: beta of chunk c at states 16kb+4q+j
    half4 bfr[4], u0h[4];
#pragma unroll
    for (int kb = 0; kb < 4; ++kb)
#pragma unroll
        for (int j = 0; j < 4; ++j) {
            int s = 16*kb + 4*q + j;
            bfr[kb][j] = (_Float16)ws[WS_PI + s];
            u0h[kb][j] = (_Float16)ws[WS_UTT0 + s];
        }

    const int tlo = (cg == 0) ? 1 : ((cg < NCH) ? 0 : 0x7fffffff);
    int tcur = t0 - W_BURN;

    float* po = out + (size_t)t0 * K + 4*q;
    float* pu = po + (size_t)T * K;
    float* pf = out + (size_t)2 * T * K + t0;

    // y comes in aligned groups of 4 (t0 and W_BURN are multiples of 4),
    // prefetched one group (4 steps) ahead. Clamped addresses feed finite
    // garbage to chunk-0 burn-in (state overridden at t=0) and tail lanes
    // (stores predicated off).
    int ib = min(max(tcur, 0), T - 4);
    f32x4 yv = *(const f32x4*)(y + ib);

#define STEP(OUTP, YCUR) do {                                                  \
    f32x4 acc[4] = {{0.f,0.f,0.f,0.f},{0.f,0.f,0.f,0.f},                       \
                    {0.f,0.f,0.f,0.f},{0.f,0.f,0.f,0.f}};                      \
    _Pragma("unroll")                                                          \
    for (int kb = 0; kb < 4; ++kb) {                                           \
        _Pragma("unroll")                                                      \
        for (int nb = 0; nb < 4; ++nb)                                         \
            acc[nb] = __builtin_amdgcn_mfma_f32_16x16x16f16(                   \
                a[nb][kb], bfr[kb], acc[nb], 0, 0, 0);                         \
    }                                                                          \
    const bool pred = (tcur >= tlo) & (tcur < T);                              \
    if (OUTP && pred) {                                                        \
        _Pragma("unroll")                                                      \
        for (int nb = 0; nb < 4; ++nb)                                         \
            *(f32x4*)(po + 16*nb) = acc[nb];                                   \
    }                                                                          \
    f32x4 nrm[4]; float st = 0.f;                                              \
    _Pragma("unroll")                                                          \
    for (int nb = 0; nb < 4; ++nb) {                                           \
        _Pragma("unroll")                                                      \
        for (int r = 0; r < 4; ++r) {                                          \
            float z  = fmaf(YCUR, isg_[nb][r], nnu_[nb][r]);                   \
            float ag = fmaf(z*z, -0.72134752f, l2n_[nb][r]);                   \
            float g  = __builtin_amdgcn_exp2f(ag);                             \
            nrm[nb][r] = acc[nb][r] * g;                                       \
            st += nrm[nb][r];                                                  \
        }                                                                      \
    }                                                                          \
    st += __shfl_xor(st, 16, 64);                                              \
    st += __shfl_xor(st, 32, 64);                                              \
    const float rs = __builtin_amdgcn_rcpf(st);                                \
    _Pragma("unroll")                                                          \
    for (int nb = 0; nb < 4; ++nb) nrm[nb] *= rs;                              \
    if (OUTP && pred) {                                                        \
        _Pragma("unroll")                                                      \
        for (int nb = 0; nb < 4; ++nb)                                         \
            *(f32x4*)(pu + 16*nb) = nrm[nb];                                   \
        if (lane < 16) *pf = st;                                               \
    }                                                                          \
    _Pragma("unroll")                                                          \
    for (int kb = 0; kb < 4; ++kb) {                                           \
        auto lo = __builtin_amdgcn_cvt_pkrtz(nrm[kb][0], nrm[kb][1]);          \
        auto hi = __builtin_amdgcn_cvt_pkrtz(nrm[kb][2], nrm[kb][3]);          \
        bfr[kb][0] = (_Float16)lo[0]; bfr[kb][1] = (_Float16)lo[1];            \
        bfr[kb][2] = (_Float16)hi[0]; bfr[kb][3] = (_Float16)hi[1];            \
    }                                                                          \
    if (OUTP) { po += K; pu += K; pf += 1; }                                   \
    ++tcur;                                                                    \
} while (0)

    // burn-in: 160 steps, no stores
#pragma unroll 1
    for (int gi = 0; gi < W_BURN/4; ++gi) {
        int ibn = min(max(tcur + 4, 0), T - 4);
        f32x4 yn = *(const f32x4*)(y + ibn);
        STEP(0, yv[0]); STEP(0, yv[1]); STEP(0, yv[2]); STEP(0, yv[3]);
        yv = yn;
    }
    // output group 0 (peeled: chunk-0 state override after t=0 step)
    {
        int ibn = min(max(tcur + 4, 0), T - 4);
        f32x4 yn = *(const f32x4*)(y + ibn);
        STEP(1, yv[0]);
        if (cg == 0) { bfr[0]=u0h[0]; bfr[1]=u0h[1]; bfr[2]=u0h[2]; bfr[3]=u0h[3]; }
        STEP(1, yv[1]); STEP(1, yv[2]); STEP(1, yv[3]);
        yv = yn;
    }
#pragma unroll 1
    for (int gi = 1; gi < S_CHUNK/4; ++gi) {
        int ibn = min(max(tcur + 4, 0), T - 4);
        f32x4 yn = *(const f32x4*)(y + ibn);
        STEP(1, yv[0]); STEP(1, yv[1]); STEP(1, yv[2]); STEP(1, yv[3]);
        yv = yn;
    }
#undef STEP
}

extern "C" void kernel_launch(void* const* d_in, const int* in_sizes, int n_in,
                              void* d_out, int out_size, void* d_ws, size_t ws_size,
                              hipStream_t stream) {
    const float* y      = (const float*)d_in[0];
    const float* logits = (const float*)d_in[1];
    const float* mu     = (const float*)d_in[2];
    const float* lsig   = (const float*)d_in[3];
    float* out = (float*)d_out;
    float* ws  = (float*)d_ws;
    const int T = in_sizes[0];

    hmm_setup<<<1, 64, 0, stream>>>(y, logits, mu, lsig, out, ws, T);

    const int nch  = (T + S_CHUNK - 1) / S_CHUNK;
    const int nblk = (nch + BATCH - 1) / BATCH;
    hmm_scan<<<nblk, 64, 0, stream>>>(y, ws, out, T);
}